// Round 1
// baseline (26896.655 us; speedup 1.0000x reference)
//
#include <hip/hip_runtime.h>

// APPNP propagation: h <- (1-alpha) * A @ h + alpha * x, K=10 steps.
// A: E=1.6M edges (row = edge_index[0], col = edge_index[1]), N=100k nodes, D=128.
// Round 0: correctness-first scatter-atomic SpMM.
//   step k: dst = 0.1*x  (init kernel, float4)
//           dst[row[e]] += 0.9*w[e]*h[col[e]]  (edge kernel, 32 lanes/edge, float4 gather + 4 fp32 HW atomics)
// Ping-pong: k even -> dst=ws, k odd -> dst=out; K=10 even so final lands in d_out.

#define N_NODES 100000
#define N_EDGES 1600000
#define D_FEAT  128
#define ALPHA   0.1f
#define K_STEPS 10

__global__ __launch_bounds__(256) void init_step(const float4* __restrict__ x,
                                                 float4* __restrict__ dst, int n4) {
    int i = blockIdx.x * 256 + threadIdx.x;
    if (i < n4) {
        float4 v = x[i];
        dst[i] = make_float4(ALPHA * v.x, ALPHA * v.y, ALPHA * v.z, ALPHA * v.w);
    }
}

// 32 lanes per edge: lane l handles features [4l, 4l+4).
__global__ __launch_bounds__(256) void edge_scatter(const int* __restrict__ rows,
                                                    const int* __restrict__ cols,
                                                    const float* __restrict__ w,
                                                    const float* __restrict__ h,
                                                    float* __restrict__ dst) {
    unsigned t = blockIdx.x * 256u + threadIdx.x;
    unsigned e = t >> 5;
    unsigned l = t & 31u;
    if (e >= N_EDGES) return;
    int r = rows[e];
    int c = cols[e];
    float we = (1.0f - ALPHA) * w[e];
    const float4* hc = (const float4*)(h + (size_t)c * D_FEAT);
    float4 v = hc[l];
    float* dr = dst + (size_t)r * D_FEAT + (size_t)l * 4;
    unsafeAtomicAdd(dr + 0, we * v.x);
    unsafeAtomicAdd(dr + 1, we * v.y);
    unsafeAtomicAdd(dr + 2, we * v.z);
    unsafeAtomicAdd(dr + 3, we * v.w);
}

extern "C" void kernel_launch(void* const* d_in, const int* in_sizes, int n_in,
                              void* d_out, int out_size, void* d_ws, size_t ws_size,
                              hipStream_t stream) {
    const float* x  = (const float*)d_in[0];
    const int*   ei = (const int*)d_in[1];   // [2, E] flat: rows then cols
    const float* ev = (const float*)d_in[2];
    const int* rows = ei;
    const int* cols = ei + N_EDGES;
    float* out = (float*)d_out;
    float* ws  = (float*)d_ws;   // needs N_NODES*D_FEAT*4 = 51.2 MB

    const int n4 = N_NODES * D_FEAT / 4;                 // 3.2M float4s
    const int init_blocks = (n4 + 255) / 256;            // 12500
    const int edge_blocks = (N_EDGES * 32 + 255) / 256;  // 200000

    for (int k = 0; k < K_STEPS; ++k) {
        const float* src = (k == 0) ? x : ((k & 1) ? ws : out);
        float* dst = (k & 1) ? out : ws;
        init_step<<<init_blocks, 256, 0, stream>>>((const float4*)x, (float4*)dst, n4);
        edge_scatter<<<edge_blocks, 256, 0, stream>>>(rows, cols, ev, src, dst);
    }
}

// Round 2
// 1759.503 us; speedup vs baseline: 15.2865x; 15.2865x over previous
//
#include <hip/hip_runtime.h>

// APPNP propagation: h <- (1-alpha) * A @ h + alpha * x, K=10 steps.
// R1: build CSR once per call (histogram + 1-block scan + scatter), then each
// step is a gather-only row reduction (1 wave/row, float2/lane, no atomics).
// R0 post-mortem: fp32 scatter-atomics wrote 3.2 GB/step through to HBM
// (WRITE_SIZE), atomic-throughput bound at 17% HBM BW. Gather form writes
// 51 MB/step and keeps h (51 MB) L3-resident.
// Ping-pong: k even -> dst=ws_h, k odd -> dst=out; K=10 even so final is d_out.

#define N_NODES 100000
#define N_EDGES 1600000
#define D_FEAT  128
#define ALPHA   0.1f
#define K_STEPS 10
#define SCAN_T  1024
#define CHUNK   ((N_NODES + SCAN_T - 1) / SCAN_T)   // 98

// ---------- CSR build ----------

__global__ __launch_bounds__(256) void hist_kernel(const int* __restrict__ rows,
                                                   int* __restrict__ deg) {
    int e = blockIdx.x * 256 + threadIdx.x;
    if (e < N_EDGES) atomicAdd(&deg[rows[e]], 1);
}

// Single-block scan: deg_cursor[i] (counts in) -> row_ptr[i] = exclusive prefix,
// deg_cursor[i] overwritten with the same prefix (becomes the scatter cursor).
__global__ __launch_bounds__(SCAN_T) void scan_kernel(int* __restrict__ deg_cursor,
                                                      int* __restrict__ row_ptr) {
    __shared__ int s[SCAN_T];
    int t = threadIdx.x;
    int lo = t * CHUNK;
    int hi = min(lo + CHUNK, N_NODES);
    int sum = 0;
    for (int i = lo; i < hi; ++i) sum += deg_cursor[i];
    s[t] = sum;
    __syncthreads();
    for (int off = 1; off < SCAN_T; off <<= 1) {
        int v = (t >= off) ? s[t - off] : 0;
        __syncthreads();
        s[t] += v;
        __syncthreads();
    }
    int run = (t == 0) ? 0 : s[t - 1];
    for (int i = lo; i < hi; ++i) {
        int d = deg_cursor[i];
        row_ptr[i] = run;
        deg_cursor[i] = run;  // cursor for scatter
        run += d;
    }
    if (t == 0) row_ptr[N_NODES] = N_EDGES;
}

__global__ __launch_bounds__(256) void scatter_kernel(const int* __restrict__ rows,
                                                      const int* __restrict__ cols,
                                                      const float* __restrict__ w,
                                                      int* __restrict__ cursor,
                                                      int* __restrict__ csr_col,
                                                      float* __restrict__ csr_w) {
    int e = blockIdx.x * 256 + threadIdx.x;
    if (e < N_EDGES) {
        int pos = atomicAdd(&cursor[rows[e]], 1);
        csr_col[pos] = cols[e];
        csr_w[pos] = (1.0f - ALPHA) * w[e];  // fold 0.9 into the edge weight
    }
}

// ---------- propagation step: one wave per row ----------

__global__ __launch_bounds__(256) void row_spmm(const int* __restrict__ row_ptr,
                                                const int* __restrict__ csr_col,
                                                const float* __restrict__ csr_w,
                                                const float2* __restrict__ x2,
                                                const float2* __restrict__ h2,
                                                float2* __restrict__ dst2) {
    int row = (blockIdx.x * 256 + threadIdx.x) >> 6;
    int lane = threadIdx.x & 63;
    if (row >= N_NODES) return;
    int beg = row_ptr[row];
    int end = row_ptr[row + 1];
    float accx = 0.0f, accy = 0.0f;
    int j = beg;
    if (j < end) {
        int c = csr_col[j];
        float wv = csr_w[j];
        for (++j; j < end; ++j) {
            int cn = csr_col[j];         // software-pipeline edge meta one ahead
            float wn = csr_w[j];
            float2 v = h2[(size_t)c * 64 + lane];
            accx += wv * v.x;
            accy += wv * v.y;
            c = cn;
            wv = wn;
        }
        float2 v = h2[(size_t)c * 64 + lane];
        accx += wv * v.x;
        accy += wv * v.y;
    }
    float2 xv = x2[(size_t)row * 64 + lane];
    float2 o;
    o.x = ALPHA * xv.x + accx;
    o.y = ALPHA * xv.y + accy;
    dst2[(size_t)row * 64 + lane] = o;
}

// ---------- fallback (R0 atomic path) if ws too small ----------

__global__ __launch_bounds__(256) void init_step(const float4* __restrict__ x,
                                                 float4* __restrict__ dst, int n4) {
    int i = blockIdx.x * 256 + threadIdx.x;
    if (i < n4) {
        float4 v = x[i];
        dst[i] = make_float4(ALPHA * v.x, ALPHA * v.y, ALPHA * v.z, ALPHA * v.w);
    }
}

__global__ __launch_bounds__(256) void edge_scatter(const int* __restrict__ rows,
                                                    const int* __restrict__ cols,
                                                    const float* __restrict__ w,
                                                    const float* __restrict__ h,
                                                    float* __restrict__ dst) {
    unsigned t = blockIdx.x * 256u + threadIdx.x;
    unsigned e = t >> 5;
    unsigned l = t & 31u;
    if (e >= N_EDGES) return;
    int r = rows[e];
    int c = cols[e];
    float we = (1.0f - ALPHA) * w[e];
    const float4* hc = (const float4*)(h + (size_t)c * D_FEAT);
    float4 v = hc[l];
    float* dr = dst + (size_t)r * D_FEAT + (size_t)l * 4;
    unsafeAtomicAdd(dr + 0, we * v.x);
    unsafeAtomicAdd(dr + 1, we * v.y);
    unsafeAtomicAdd(dr + 2, we * v.z);
    unsafeAtomicAdd(dr + 3, we * v.w);
}

extern "C" void kernel_launch(void* const* d_in, const int* in_sizes, int n_in,
                              void* d_out, int out_size, void* d_ws, size_t ws_size,
                              hipStream_t stream) {
    const float* x  = (const float*)d_in[0];
    const int*   ei = (const int*)d_in[1];  // [2, E] flat: rows then cols (int32 per harness)
    const float* ev = (const float*)d_in[2];
    const int* rows = ei;
    const int* cols = ei + N_EDGES;
    float* out = (float*)d_out;

    // ws layout (16B-aligned chunks)
    size_t off = 0;
    auto take = [&](size_t bytes) {
        size_t o = off;
        off = (off + bytes + 15) & ~(size_t)15;
        return o;
    };
    size_t o_h      = take((size_t)N_NODES * D_FEAT * 4);  // 51.2 MB ping buffer
    size_t o_rowptr = take((size_t)(N_NODES + 1) * 4);
    size_t o_cursor = take((size_t)N_NODES * 4);           // deg, then cursor
    size_t o_col    = take((size_t)N_EDGES * 4);
    size_t o_w      = take((size_t)N_EDGES * 4);
    size_t need = off;

    const int edge_blocks_1t = (N_EDGES + 255) / 256;  // 6250

    if (ws_size >= need) {
        char* ws = (char*)d_ws;
        float* h_ws    = (float*)(ws + o_h);
        int*   row_ptr = (int*)(ws + o_rowptr);
        int*   cursor  = (int*)(ws + o_cursor);
        int*   csr_col = (int*)(ws + o_col);
        float* csr_w   = (float*)(ws + o_w);

        // CSR build (every call — ws is re-poisoned by the harness)
        hipMemsetAsync(cursor, 0, (size_t)N_NODES * 4, stream);
        hist_kernel<<<edge_blocks_1t, 256, 0, stream>>>(rows, cursor);
        scan_kernel<<<1, SCAN_T, 0, stream>>>(cursor, row_ptr);
        scatter_kernel<<<edge_blocks_1t, 256, 0, stream>>>(rows, cols, ev, cursor,
                                                           csr_col, csr_w);

        const int row_blocks = (N_NODES * 64 + 255) / 256;  // 25000 (1 wave/row)
        for (int k = 0; k < K_STEPS; ++k) {
            const float* src = (k == 0) ? x : ((k & 1) ? h_ws : out);
            float* dst = (k & 1) ? out : h_ws;
            row_spmm<<<row_blocks, 256, 0, stream>>>(row_ptr, csr_col, csr_w,
                                                     (const float2*)x,
                                                     (const float2*)src,
                                                     (float2*)dst);
        }
    } else {
        // Fallback: R0 atomic path (needs only the 51.2 MB ping buffer)
        float* ws = (float*)d_ws;
        const int n4 = N_NODES * D_FEAT / 4;
        const int init_blocks = (n4 + 255) / 256;
        const int edge_blocks = (N_EDGES * 32 + 255) / 256;
        for (int k = 0; k < K_STEPS; ++k) {
            const float* src = (k == 0) ? x : ((k & 1) ? ws : out);
            float* dst = (k & 1) ? out : ws;
            init_step<<<init_blocks, 256, 0, stream>>>((const float4*)x, (float4*)dst, n4);
            edge_scatter<<<edge_blocks, 256, 0, stream>>>(rows, cols, ev, src, dst);
        }
    }
}

// Round 3
// 1546.231 us; speedup vs baseline: 17.3950x; 1.1379x over previous
//
#include <hip/hip_runtime.h>

// APPNP propagation: h <- (1-alpha) * A @ h + alpha * x, K=10 steps.
// R2: R1's CSR+gather structure, with
//  - hierarchical 3-kernel scan (R1's single-block scan was 230 us, 13% of total)
//  - packed (col,w) int2 CSR entries (halves scattered stores + edge-meta loads)
//  - row_spmm edge loop unrolled x2 (more outstanding gathers per wave)
// Ping-pong: k even -> dst=ws_h, k odd -> dst=out; K=10 even so final is d_out.

#define N_NODES 100000
#define N_EDGES 1600000
#define D_FEAT  128
#define ALPHA   0.1f
#define K_STEPS 10

#define SCAN_ELEMS 512
#define SCAN_NBLK  ((N_NODES + SCAN_ELEMS - 1) / SCAN_ELEMS)  // 196

// ---------- CSR build ----------

__global__ __launch_bounds__(256) void hist_kernel(const int* __restrict__ rows,
                                                   int* __restrict__ deg) {
    int e = blockIdx.x * 256 + threadIdx.x;
    if (e < N_EDGES) atomicAdd(&deg[rows[e]], 1);
}

// Pass 1: per-block sums of 512-element chunks.
__global__ __launch_bounds__(256) void scan_partial(const int* __restrict__ deg,
                                                    int* __restrict__ partial) {
    __shared__ int s[256];
    int b = blockIdx.x, t = threadIdx.x;
    int i0 = b * SCAN_ELEMS + t * 2;
    int v0 = (i0 < N_NODES) ? deg[i0] : 0;
    int v1 = (i0 + 1 < N_NODES) ? deg[i0 + 1] : 0;
    s[t] = v0 + v1;
    __syncthreads();
    for (int off = 128; off > 0; off >>= 1) {
        if (t < off) s[t] += s[t + off];
        __syncthreads();
    }
    if (t == 0) partial[b] = s[0];
}

// Pass 2: exclusive scan of the 196 partials (one block).
__global__ __launch_bounds__(256) void scan_top(int* __restrict__ partial) {
    __shared__ int s[256];
    int t = threadIdx.x;
    s[t] = (t < SCAN_NBLK) ? partial[t] : 0;
    __syncthreads();
    for (int off = 1; off < 256; off <<= 1) {
        int v = (t >= off) ? s[t - off] : 0;
        __syncthreads();
        s[t] += v;
        __syncthreads();
    }
    if (t < SCAN_NBLK) partial[t] = (t == 0) ? 0 : s[t - 1];
}

// Pass 3: per-chunk exclusive scan + global offset; writes row_ptr and
// overwrites deg in-place as the scatter cursor (each element is read by the
// same thread that writes it, after all the block's reads).
__global__ __launch_bounds__(256) void scan_final(int* __restrict__ deg_cursor,
                                                  const int* __restrict__ partial,
                                                  int* __restrict__ row_ptr) {
    __shared__ int s[256];
    int b = blockIdx.x, t = threadIdx.x;
    int i0 = b * SCAN_ELEMS + t * 2;
    int v0 = (i0 < N_NODES) ? deg_cursor[i0] : 0;
    int v1 = (i0 + 1 < N_NODES) ? deg_cursor[i0 + 1] : 0;
    int pair = v0 + v1;
    s[t] = pair;
    __syncthreads();
    for (int off = 1; off < 256; off <<= 1) {
        int v = (t >= off) ? s[t - off] : 0;
        __syncthreads();
        s[t] += v;
        __syncthreads();
    }
    int ex = partial[b] + s[t] - pair;  // exclusive prefix of element 2t
    if (i0 < N_NODES)     { row_ptr[i0] = ex;          deg_cursor[i0] = ex; }
    if (i0 + 1 < N_NODES) { row_ptr[i0 + 1] = ex + v0; deg_cursor[i0 + 1] = ex + v0; }
    if (b == 0 && t == 0) row_ptr[N_NODES] = N_EDGES;
}

__global__ __launch_bounds__(256) void scatter_kernel(const int* __restrict__ rows,
                                                      const int* __restrict__ cols,
                                                      const float* __restrict__ w,
                                                      int* __restrict__ cursor,
                                                      int2* __restrict__ csr) {
    int e = blockIdx.x * 256 + threadIdx.x;
    if (e < N_EDGES) {
        int pos = atomicAdd(&cursor[rows[e]], 1);
        int2 cw;
        cw.x = cols[e];
        cw.y = __float_as_int((1.0f - ALPHA) * w[e]);  // fold 0.9 into the weight
        csr[pos] = cw;
    }
}

// ---------- propagation step: one wave per row ----------

__global__ __launch_bounds__(256) void row_spmm(const int* __restrict__ row_ptr,
                                                const int2* __restrict__ csr,
                                                const float2* __restrict__ x2,
                                                const float2* __restrict__ h2,
                                                float2* __restrict__ dst2) {
    int row = (blockIdx.x * 256 + threadIdx.x) >> 6;
    int lane = threadIdx.x & 63;
    if (row >= N_NODES) return;
    int beg = row_ptr[row];
    int end = row_ptr[row + 1];
    float ax0 = 0.0f, ay0 = 0.0f, ax1 = 0.0f, ay1 = 0.0f;
    int j = beg;
    for (; j + 1 < end; j += 2) {
        int2 cw0 = csr[j];
        int2 cw1 = csr[j + 1];
        float2 v0 = h2[(size_t)cw0.x * 64 + lane];
        float2 v1 = h2[(size_t)cw1.x * 64 + lane];
        float w0 = __int_as_float(cw0.y);
        float w1 = __int_as_float(cw1.y);
        ax0 += w0 * v0.x; ay0 += w0 * v0.y;
        ax1 += w1 * v1.x; ay1 += w1 * v1.y;
    }
    if (j < end) {
        int2 cw = csr[j];
        float2 v = h2[(size_t)cw.x * 64 + lane];
        float wv = __int_as_float(cw.y);
        ax0 += wv * v.x; ay0 += wv * v.y;
    }
    float2 xv = x2[(size_t)row * 64 + lane];
    float2 o;
    o.x = ALPHA * xv.x + ax0 + ax1;
    o.y = ALPHA * xv.y + ay0 + ay1;
    dst2[(size_t)row * 64 + lane] = o;
}

// ---------- fallback (R0 atomic path) if ws too small ----------

__global__ __launch_bounds__(256) void init_step(const float4* __restrict__ x,
                                                 float4* __restrict__ dst, int n4) {
    int i = blockIdx.x * 256 + threadIdx.x;
    if (i < n4) {
        float4 v = x[i];
        dst[i] = make_float4(ALPHA * v.x, ALPHA * v.y, ALPHA * v.z, ALPHA * v.w);
    }
}

__global__ __launch_bounds__(256) void edge_scatter(const int* __restrict__ rows,
                                                    const int* __restrict__ cols,
                                                    const float* __restrict__ w,
                                                    const float* __restrict__ h,
                                                    float* __restrict__ dst) {
    unsigned t = blockIdx.x * 256u + threadIdx.x;
    unsigned e = t >> 5;
    unsigned l = t & 31u;
    if (e >= N_EDGES) return;
    int r = rows[e];
    int c = cols[e];
    float we = (1.0f - ALPHA) * w[e];
    const float4* hc = (const float4*)(h + (size_t)c * D_FEAT);
    float4 v = hc[l];
    float* dr = dst + (size_t)r * D_FEAT + (size_t)l * 4;
    unsafeAtomicAdd(dr + 0, we * v.x);
    unsafeAtomicAdd(dr + 1, we * v.y);
    unsafeAtomicAdd(dr + 2, we * v.z);
    unsafeAtomicAdd(dr + 3, we * v.w);
}

extern "C" void kernel_launch(void* const* d_in, const int* in_sizes, int n_in,
                              void* d_out, int out_size, void* d_ws, size_t ws_size,
                              hipStream_t stream) {
    const float* x  = (const float*)d_in[0];
    const int*   ei = (const int*)d_in[1];  // [2, E] flat: rows then cols
    const float* ev = (const float*)d_in[2];
    const int* rows = ei;
    const int* cols = ei + N_EDGES;
    float* out = (float*)d_out;

    // ws layout (16B-aligned chunks)
    size_t off = 0;
    auto take = [&](size_t bytes) {
        size_t o = off;
        off = (off + bytes + 15) & ~(size_t)15;
        return o;
    };
    size_t o_h       = take((size_t)N_NODES * D_FEAT * 4);  // 51.2 MB ping buffer
    size_t o_rowptr  = take((size_t)(N_NODES + 1) * 4);
    size_t o_cursor  = take((size_t)N_NODES * 4);           // deg, then cursor
    size_t o_partial = take((size_t)SCAN_NBLK * 4);
    size_t o_csr     = take((size_t)N_EDGES * 8);           // packed (col, w)
    size_t need = off;

    const int edge_blocks_1t = (N_EDGES + 255) / 256;  // 6250

    if (ws_size >= need) {
        char* ws = (char*)d_ws;
        float* h_ws    = (float*)(ws + o_h);
        int*   row_ptr = (int*)(ws + o_rowptr);
        int*   cursor  = (int*)(ws + o_cursor);
        int*   partial = (int*)(ws + o_partial);
        int2*  csr     = (int2*)(ws + o_csr);

        // CSR build (every call — ws is re-poisoned by the harness)
        hipMemsetAsync(cursor, 0, (size_t)N_NODES * 4, stream);
        hist_kernel<<<edge_blocks_1t, 256, 0, stream>>>(rows, cursor);
        scan_partial<<<SCAN_NBLK, 256, 0, stream>>>(cursor, partial);
        scan_top<<<1, 256, 0, stream>>>(partial);
        scan_final<<<SCAN_NBLK, 256, 0, stream>>>(cursor, partial, row_ptr);
        scatter_kernel<<<edge_blocks_1t, 256, 0, stream>>>(rows, cols, ev, cursor, csr);

        const int row_blocks = (N_NODES * 64 + 255) / 256;  // 25000 (1 wave/row)
        for (int k = 0; k < K_STEPS; ++k) {
            const float* src = (k == 0) ? x : ((k & 1) ? h_ws : out);
            float* dst = (k & 1) ? out : h_ws;
            row_spmm<<<row_blocks, 256, 0, stream>>>(row_ptr, csr,
                                                     (const float2*)x,
                                                     (const float2*)src,
                                                     (float2*)dst);
        }
    } else {
        // Fallback: R0 atomic path (needs only the 51.2 MB ping buffer)
        float* ws = (float*)d_ws;
        const int n4 = N_NODES * D_FEAT / 4;
        const int init_blocks = (n4 + 255) / 256;
        const int edge_blocks = (N_EDGES * 32 + 255) / 256;
        for (int k = 0; k < K_STEPS; ++k) {
            const float* src = (k == 0) ? x : ((k & 1) ? ws : out);
            float* dst = (k & 1) ? out : ws;
            init_step<<<init_blocks, 256, 0, stream>>>((const float4*)x, (float4*)dst, n4);
            edge_scatter<<<edge_blocks, 256, 0, stream>>>(rows, cols, ev, src, dst);
        }
    }
}

// Round 4
// 1066.631 us; speedup vs baseline: 25.2165x; 1.4496x over previous
//
#include <hip/hip_runtime.h>

// APPNP propagation: h <- (1-alpha) * A @ h + alpha * x, K=10 steps.
// R3: CSR gather structure from R2, with bf16 intermediate h buffers.
// R2 post-mortem: row_spmm = 88% of time, FETCH_SIZE 404 MB/step vs 819 MB
// logical gathers -> bound by L2-miss gather traffic (h=51MB >> 4MB/XCD L2).
// bf16 h halves gather bytes AND halves h's cache footprint (25.6 MB fits
// aggregate 32 MB L2). Accumulate fp32, round once per step; x stays fp32;
// final step writes fp32 to d_out. Edge loop unrolled x4 for outstanding loads.

#define N_NODES 100000
#define N_EDGES 1600000
#define D_FEAT  128
#define ALPHA   0.1f
#define K_STEPS 10

#define SCAN_ELEMS 512
#define SCAN_NBLK  ((N_NODES + SCAN_ELEMS - 1) / SCAN_ELEMS)  // 196

static __device__ __forceinline__ float bf2f(unsigned u16) {
    return __uint_as_float(u16 << 16);
}
static __device__ __forceinline__ unsigned f2bf(float f) {
    unsigned u = __float_as_uint(f);
    return (u + 0x7fffu + ((u >> 16) & 1u)) >> 16;  // round-to-nearest-even
}

// ---------- CSR build ----------

__global__ __launch_bounds__(256) void hist_kernel(const int* __restrict__ rows,
                                                   int* __restrict__ deg) {
    int e = blockIdx.x * 256 + threadIdx.x;
    if (e < N_EDGES) atomicAdd(&deg[rows[e]], 1);
}

__global__ __launch_bounds__(256) void scan_partial(const int* __restrict__ deg,
                                                    int* __restrict__ partial) {
    __shared__ int s[256];
    int b = blockIdx.x, t = threadIdx.x;
    int i0 = b * SCAN_ELEMS + t * 2;
    int v0 = (i0 < N_NODES) ? deg[i0] : 0;
    int v1 = (i0 + 1 < N_NODES) ? deg[i0 + 1] : 0;
    s[t] = v0 + v1;
    __syncthreads();
    for (int off = 128; off > 0; off >>= 1) {
        if (t < off) s[t] += s[t + off];
        __syncthreads();
    }
    if (t == 0) partial[b] = s[0];
}

__global__ __launch_bounds__(256) void scan_top(int* __restrict__ partial) {
    __shared__ int s[256];
    int t = threadIdx.x;
    s[t] = (t < SCAN_NBLK) ? partial[t] : 0;
    __syncthreads();
    for (int off = 1; off < 256; off <<= 1) {
        int v = (t >= off) ? s[t - off] : 0;
        __syncthreads();
        s[t] += v;
        __syncthreads();
    }
    if (t < SCAN_NBLK) partial[t] = (t == 0) ? 0 : s[t - 1];
}

__global__ __launch_bounds__(256) void scan_final(int* __restrict__ deg_cursor,
                                                  const int* __restrict__ partial,
                                                  int* __restrict__ row_ptr) {
    __shared__ int s[256];
    int b = blockIdx.x, t = threadIdx.x;
    int i0 = b * SCAN_ELEMS + t * 2;
    int v0 = (i0 < N_NODES) ? deg_cursor[i0] : 0;
    int v1 = (i0 + 1 < N_NODES) ? deg_cursor[i0 + 1] : 0;
    int pair = v0 + v1;
    s[t] = pair;
    __syncthreads();
    for (int off = 1; off < 256; off <<= 1) {
        int v = (t >= off) ? s[t - off] : 0;
        __syncthreads();
        s[t] += v;
        __syncthreads();
    }
    int ex = partial[b] + s[t] - pair;  // exclusive prefix of element 2t
    if (i0 < N_NODES)     { row_ptr[i0] = ex;          deg_cursor[i0] = ex; }
    if (i0 + 1 < N_NODES) { row_ptr[i0 + 1] = ex + v0; deg_cursor[i0 + 1] = ex + v0; }
    if (b == 0 && t == 0) row_ptr[N_NODES] = N_EDGES;
}

__global__ __launch_bounds__(256) void scatter_kernel(const int* __restrict__ rows,
                                                      const int* __restrict__ cols,
                                                      const float* __restrict__ w,
                                                      int* __restrict__ cursor,
                                                      int2* __restrict__ csr) {
    int e = blockIdx.x * 256 + threadIdx.x;
    if (e < N_EDGES) {
        int pos = atomicAdd(&cursor[rows[e]], 1);
        int2 cw;
        cw.x = cols[e];
        cw.y = __float_as_int((1.0f - ALPHA) * w[e]);  // fold 0.9 into the weight
        csr[pos] = cw;
    }
}

// ---------- propagation step: one wave per row ----------
// SRC_BF/DST_BF select bf16 (packed 2xbf16 per lane, 4 B) vs fp32 (float2, 8 B).

template <bool SRC_BF, bool DST_BF>
__global__ __launch_bounds__(256) void row_spmm_t(const int* __restrict__ row_ptr,
                                                  const int2* __restrict__ csr,
                                                  const float2* __restrict__ x2,
                                                  const void* __restrict__ src,
                                                  void* __restrict__ dst) {
    int row = (blockIdx.x * 256 + threadIdx.x) >> 6;
    int lane = threadIdx.x & 63;
    if (row >= N_NODES) return;
    int beg = row_ptr[row];
    int end = row_ptr[row + 1];
    float2 xv = x2[(size_t)row * 64 + lane];  // issue early, overlaps gathers

    const float2*   sf = (const float2*)src;
    const unsigned* sb = (const unsigned*)src;

    float ax0 = 0, ay0 = 0, ax1 = 0, ay1 = 0, ax2 = 0, ay2 = 0, ax3 = 0, ay3 = 0;

    auto gather = [&](int col) -> float2 {
        if (SRC_BF) {
            unsigned u = sb[(size_t)col * 64 + lane];
            float2 v;
            v.x = bf2f(u & 0xffffu);
            v.y = bf2f(u >> 16);
            return v;
        } else {
            return sf[(size_t)col * 64 + lane];
        }
    };

    int j = beg;
    for (; j + 3 < end; j += 4) {
        int2 cw0 = csr[j], cw1 = csr[j + 1], cw2 = csr[j + 2], cw3 = csr[j + 3];
        float2 v0 = gather(cw0.x);
        float2 v1 = gather(cw1.x);
        float2 v2 = gather(cw2.x);
        float2 v3 = gather(cw3.x);
        float w0 = __int_as_float(cw0.y), w1 = __int_as_float(cw1.y);
        float w2 = __int_as_float(cw2.y), w3 = __int_as_float(cw3.y);
        ax0 += w0 * v0.x; ay0 += w0 * v0.y;
        ax1 += w1 * v1.x; ay1 += w1 * v1.y;
        ax2 += w2 * v2.x; ay2 += w2 * v2.y;
        ax3 += w3 * v3.x; ay3 += w3 * v3.y;
    }
    for (; j < end; ++j) {
        int2 cw = csr[j];
        float2 v = gather(cw.x);
        float wv = __int_as_float(cw.y);
        ax0 += wv * v.x; ay0 += wv * v.y;
    }

    float ox = ALPHA * xv.x + (ax0 + ax1) + (ax2 + ax3);
    float oy = ALPHA * xv.y + (ay0 + ay1) + (ay2 + ay3);

    if (DST_BF) {
        ((unsigned*)dst)[(size_t)row * 64 + lane] = f2bf(ox) | (f2bf(oy) << 16);
    } else {
        float2 o; o.x = ox; o.y = oy;
        ((float2*)dst)[(size_t)row * 64 + lane] = o;
    }
}

// ---------- fallback (R0 atomic path) if ws too small ----------

__global__ __launch_bounds__(256) void init_step(const float4* __restrict__ x,
                                                 float4* __restrict__ dst, int n4) {
    int i = blockIdx.x * 256 + threadIdx.x;
    if (i < n4) {
        float4 v = x[i];
        dst[i] = make_float4(ALPHA * v.x, ALPHA * v.y, ALPHA * v.z, ALPHA * v.w);
    }
}

__global__ __launch_bounds__(256) void edge_scatter(const int* __restrict__ rows,
                                                    const int* __restrict__ cols,
                                                    const float* __restrict__ w,
                                                    const float* __restrict__ h,
                                                    float* __restrict__ dst) {
    unsigned t = blockIdx.x * 256u + threadIdx.x;
    unsigned e = t >> 5;
    unsigned l = t & 31u;
    if (e >= N_EDGES) return;
    int r = rows[e];
    int c = cols[e];
    float we = (1.0f - ALPHA) * w[e];
    const float4* hc = (const float4*)(h + (size_t)c * D_FEAT);
    float4 v = hc[l];
    float* dr = dst + (size_t)r * D_FEAT + (size_t)l * 4;
    unsafeAtomicAdd(dr + 0, we * v.x);
    unsafeAtomicAdd(dr + 1, we * v.y);
    unsafeAtomicAdd(dr + 2, we * v.z);
    unsafeAtomicAdd(dr + 3, we * v.w);
}

extern "C" void kernel_launch(void* const* d_in, const int* in_sizes, int n_in,
                              void* d_out, int out_size, void* d_ws, size_t ws_size,
                              hipStream_t stream) {
    const float* x  = (const float*)d_in[0];
    const int*   ei = (const int*)d_in[1];  // [2, E] flat: rows then cols
    const float* ev = (const float*)d_in[2];
    const int* rows = ei;
    const int* cols = ei + N_EDGES;
    float* out = (float*)d_out;

    // ws layout (16B-aligned chunks)
    size_t off = 0;
    auto take = [&](size_t bytes) {
        size_t o = off;
        off = (off + bytes + 15) & ~(size_t)15;
        return o;
    };
    size_t o_ha      = take((size_t)N_NODES * D_FEAT * 2);  // 25.6 MB bf16 ping
    size_t o_hb      = take((size_t)N_NODES * D_FEAT * 2);  // 25.6 MB bf16 pong
    size_t o_rowptr  = take((size_t)(N_NODES + 1) * 4);
    size_t o_cursor  = take((size_t)N_NODES * 4);           // deg, then cursor
    size_t o_partial = take((size_t)SCAN_NBLK * 4);
    size_t o_csr     = take((size_t)N_EDGES * 8);           // packed (col, w)
    size_t need = off;

    const int edge_blocks_1t = (N_EDGES + 255) / 256;  // 6250

    if (ws_size >= need) {
        char* ws = (char*)d_ws;
        void*  h_a     = (void*)(ws + o_ha);
        void*  h_b     = (void*)(ws + o_hb);
        int*   row_ptr = (int*)(ws + o_rowptr);
        int*   cursor  = (int*)(ws + o_cursor);
        int*   partial = (int*)(ws + o_partial);
        int2*  csr     = (int2*)(ws + o_csr);

        // CSR build (every call — ws is re-poisoned by the harness)
        hipMemsetAsync(cursor, 0, (size_t)N_NODES * 4, stream);
        hist_kernel<<<edge_blocks_1t, 256, 0, stream>>>(rows, cursor);
        scan_partial<<<SCAN_NBLK, 256, 0, stream>>>(cursor, partial);
        scan_top<<<1, 256, 0, stream>>>(partial);
        scan_final<<<SCAN_NBLK, 256, 0, stream>>>(cursor, partial, row_ptr);
        scatter_kernel<<<edge_blocks_1t, 256, 0, stream>>>(rows, cols, ev, cursor, csr);

        const int row_blocks = (N_NODES * 64 + 255) / 256;  // 25000 (1 wave/row)
        const float2* x2 = (const float2*)x;

        // k=0: fp32 x -> bf16 h_a
        row_spmm_t<false, true><<<row_blocks, 256, 0, stream>>>(
            row_ptr, csr, x2, (const void*)x, h_a);
        // k=1..8: bf16 -> bf16, ping-pong (dst: b,a,b,a,b,a,b,a)
        for (int k = 1; k <= 8; ++k) {
            const void* src = (k & 1) ? h_a : h_b;
            void* dst = (k & 1) ? h_b : h_a;
            row_spmm_t<true, true><<<row_blocks, 256, 0, stream>>>(
                row_ptr, csr, x2, src, dst);
        }
        // k=9: bf16 h_a -> fp32 out
        row_spmm_t<true, false><<<row_blocks, 256, 0, stream>>>(
            row_ptr, csr, x2, (const void*)h_a, (void*)out);
    } else {
        // Fallback: R0 atomic path (needs only the 51.2 MB ping buffer)
        float* wsf = (float*)d_ws;
        const int n4 = N_NODES * D_FEAT / 4;
        const int init_blocks = (n4 + 255) / 256;
        const int edge_blocks = (N_EDGES * 32 + 255) / 256;
        for (int k = 0; k < K_STEPS; ++k) {
            const float* src = (k == 0) ? x : ((k & 1) ? wsf : out);
            float* dst = (k & 1) ? out : wsf;
            init_step<<<init_blocks, 256, 0, stream>>>((const float4*)x, (float4*)dst, n4);
            edge_scatter<<<edge_blocks, 256, 0, stream>>>(rows, cols, ev, src, dst);
        }
    }
}